// Round 1
// baseline (223.309 us; speedup 1.0000x reference)
//
#include <hip/hip_runtime.h>
#include <stdint.h>

#define FD 128   // feature dim
#define NG 8     // graphs
#define NC 10    // classes
#define MAXB 1024           // max buckets
#define CHUNK 4096          // edges per counting chunk

typedef __attribute__((ext_vector_type(8))) short bf16x8;
typedef __attribute__((ext_vector_type(4))) float f32x4;
typedef __attribute__((ext_vector_type(2))) float f32x2;

__device__ __forceinline__ float bf2f(uint16_t u){
    union { uint32_t i; float f; } v; v.i = ((uint32_t)u) << 16; return v.f;
}
__device__ __forceinline__ uint16_t f2bf(float f){
    union { float f; uint32_t i; } v; v.f = f;
    uint32_t r = v.i + 0x7fff + ((v.i >> 16) & 1);
    return (uint16_t)(r >> 16);
}

// ---- fp8 e4m3 conversions (HW path with manual fallback) ----
#if __has_builtin(__builtin_amdgcn_cvt_pk_f32_fp8) && __has_builtin(__builtin_amdgcn_cvt_pk_fp8_f32)
__device__ __forceinline__ f32x2 fp8lo2f(uint32_t p){
    return __builtin_amdgcn_cvt_pk_f32_fp8((int)p, false);
}
__device__ __forceinline__ f32x2 fp8hi2f(uint32_t p){
    return __builtin_amdgcn_cvt_pk_f32_fp8((int)p, true);
}
__device__ __forceinline__ uint32_t pk4fp8(float a, float b, float c, float d){
    int u = 0;
    u = __builtin_amdgcn_cvt_pk_fp8_f32(a, b, u, false);
    u = __builtin_amdgcn_cvt_pk_fp8_f32(c, d, u, true);
    return (uint32_t)u;
}
#else
__device__ __forceinline__ float fp8tof(uint32_t b){
    union { uint32_t i; float f; } v;
    v.i = ((b & 0x7f) << 20) | ((b & 0x80) << 24);
    return v.f * 0x1p120f;
}
__device__ __forceinline__ f32x2 fp8lo2f(uint32_t p){
    return (f32x2){fp8tof(p & 0xff), fp8tof((p >> 8) & 0xff)};
}
__device__ __forceinline__ f32x2 fp8hi2f(uint32_t p){
    return (f32x2){fp8tof((p >> 16) & 0xff), fp8tof((p >> 24) & 0xff)};
}
__device__ __forceinline__ uint32_t f2fp8(float f){
    union { float f; uint32_t i; } v; v.f = f;
    uint32_t s = (v.i >> 24) & 0x80;
    float a = fabsf(f);
    if (a < 0x1p-10f) return s;
    if (a > 448.f) return s | 0x7e;
    v.f = a;
    uint32_t r = v.i + 0x7ffff + ((v.i >> 20) & 1);
    int e = (int)(r >> 23) - 127 + 7;
    uint32_t m = (r >> 20) & 7;
    if (e <= 0){
        uint32_t q = (uint32_t)(a * 512.f + 0.5f);
        return s | (q > 7 ? 8 : q);
    }
    if (e > 15) return s | 0x7e;
    return s | ((uint32_t)e << 3) | m;
}
__device__ __forceinline__ uint32_t pk4fp8(float a, float b, float c, float d){
    return (uint32_t)f2fp8(a) | ((uint32_t)f2fp8(b)<<8) |
           ((uint32_t)f2fp8(c)<<16) | ((uint32_t)f2fp8(d)<<24);
}
#endif

// ============ Fused: prep_w + per-chunk histograms + zero-init ============
__global__ __launch_bounds__(256) void k_prep(const float* __restrict__ W1,
        const float* __restrict__ W2, uint16_t* Wf1, uint16_t* Wf2,
        const int* __restrict__ ei, int E, int B, int C, int shift,
        int* __restrict__ cnt, float* __restrict__ pool,
        unsigned long long* __restrict__ state, int* __restrict__ counters){
    int t = threadIdx.x;
    if (blockIdx.x < 128){
        int id = blockIdx.x*256 + t;
        int w = id >> 14;
        int r = id & 16383;
        int j = r & 7, frag = r >> 3;
        int lane = frag & 63, t2 = frag >> 6;
        int n = t2 & 7, kk = t2 >> 3;
        int k = kk*32 + (lane>>4)*8 + j;
        int col = n*16 + (lane&15);
        float v = (w ? W2 : W1)[k*128 + col];
        (w ? Wf2 : Wf1)[r] = f2bf(v);
        if (blockIdx.x == 0){
            for (int i = t; i < NG*FD; i += 256) pool[i] = 0.f;
            for (int i = t; i < 1024; i += 256) state[i] = 0ull;
            if (t < 8) counters[t] = 0;
        }
        return;
    }
    __shared__ int hd[MAXB], hs[MAXB];
    int c = blockIdx.x - 128;
    for (int i=t;i<B;i+=256){ hd[i]=0; hs[i]=0; }
    __syncthreads();
    int e0 = c*CHUNK, e1 = min(E, e0+CHUNK);
    for (int e = e0+t; e < e1; e += 256){
        int s = ei[e], d = ei[E+e];
        atomicAdd(&hd[d>>shift], 1);
        atomicAdd(&hs[s>>shift], 1);
    }
    __syncthreads();
    for (int i=t;i<B;i+=256){
        cnt[(size_t)i*C + c]     = hd[i];
        cnt[(size_t)(B+i)*C + c] = hs[i];
    }
}

// ============ single-pass exclusive scan (decoupled lookback) ============
#define SEPT 16
#define STILE 4096
__global__ __launch_bounds__(256) void k_scan(int* __restrict__ a, int M,
        unsigned long long* __restrict__ state, int* __restrict__ ticket){
    __shared__ int bid_s, exc_s;
    __shared__ int s[256];
    int t = threadIdx.x;
    if (t == 0) bid_s = atomicAdd(ticket, 1);
    __syncthreads();
    int bid = bid_s;
    int base = bid*STILE + t*SEPT;
    int v[SEPT]; int sum = 0;
    #pragma unroll
    for (int i=0;i<SEPT;i++){ int idx=base+i; int x=(idx<M)?a[idx]:0; v[i]=sum; sum+=x; }
    s[t]=sum; __syncthreads();
    for (int o=1;o<256;o<<=1){ int x=(t>=o)?s[t-o]:0; __syncthreads(); s[t]+=x; __syncthreads(); }
    int tot = s[255];
    int te = s[t]-sum;
    if (t == 0){
        unsigned long long pub = ((bid==0) ? (2ull<<62) : (1ull<<62)) | (unsigned long long)(unsigned)tot;
        __hip_atomic_store(&state[bid], pub, __ATOMIC_RELEASE, __HIP_MEMORY_SCOPE_AGENT);
        int exc = 0;
        if (bid > 0){
            int p = bid-1;
            while (true){
                unsigned long long st = __hip_atomic_load(&state[p], __ATOMIC_ACQUIRE, __HIP_MEMORY_SCOPE_AGENT);
                unsigned long long fl = st >> 62;
                if (fl == 2ull){ exc += (int)(unsigned)st; break; }
                if (fl == 1ull){ exc += (int)(unsigned)st; p--; }
            }
            __hip_atomic_store(&state[bid],
                (2ull<<62) | (unsigned long long)(unsigned)(exc + tot),
                __ATOMIC_RELEASE, __HIP_MEMORY_SCOPE_AGENT);
        }
        exc_s = exc;
    }
    __syncthreads();
    int exc = exc_s;
    #pragma unroll
    for (int i=0;i<SEPT;i++){ int idx=base+i; if (idx<M) a[idx]=exc+te+v[i]; }
}

// ============ scatter edges into bucket-grouped temps ============
__global__ __launch_bounds__(256) void k_scatter(const int* __restrict__ ei, int E,
        int B, int C, int shift, const int* __restrict__ scan,
        uint32_t* __restrict__ tempD, uint16_t* __restrict__ tempS){
    __shared__ int cd[MAXB], cs[MAXB];
    int t = threadIdx.x, c = blockIdx.x;
    for (int i=t;i<B;i+=256){
        cd[i] = scan[(size_t)i*C + c];
        cs[i] = scan[(size_t)(B+i)*C + c] - E;
    }
    __syncthreads();
    int e0 = c*CHUNK, e1 = min(E, e0+CHUNK);
    int lmask = (1<<shift) - 1;
    for (int e = e0+t; e < e1; e += 256){
        int s = ei[e], d = ei[E+e];
        int p = atomicAdd(&cd[d>>shift], 1);
        tempD[p] = ((uint32_t)(d & lmask) << 20) | (uint32_t)s;
        int q = atomicAdd(&cs[s>>shift], 1);
        tempS[q] = (uint16_t)s;
    }
}

// ============ per-bucket: row_off + csr (dst) and deg_out (src) ============
__global__ __launch_bounds__(256) void k_build2(const uint32_t* __restrict__ tempD,
        const uint16_t* __restrict__ tempS, const int* __restrict__ scan,
        int B, int C, int shift, int E, int N,
        int* __restrict__ row_off, int* __restrict__ csr, int* __restrict__ deg_out){
    __shared__ int cnt[MAXB];
    __shared__ int offl[MAXB];
    int b = blockIdx.x, t = threadIdx.x;
    int range = 1<<shift, nb0 = b<<shift;
    int seg0 = scan[(size_t)b*C];
    int seg1 = (b+1<B) ? scan[(size_t)(b+1)*C] : E;
    for (int i=t;i<range;i+=256) cnt[i]=0;
    __syncthreads();
    for (int i=seg0+t; i<seg1; i+=256)
        atomicAdd(&cnt[tempD[i]>>20], 1);
    __syncthreads();
    if (t==0){ int run=0; for (int i=0;i<range;i++){ offl[i]=run; run+=cnt[i]; } }
    __syncthreads();
    for (int i=t;i<range;i+=256){
        int node = nb0+i;
        if (node < N) row_off[node] = seg0 + offl[i];
    }
    if (b==B-1 && t==0) row_off[N] = E;
    for (int i=t;i<range;i+=256) cnt[i] = offl[i];
    __syncthreads();
    for (int i=seg0+t; i<seg1; i+=256){
        uint32_t v = tempD[i];
        int p = atomicAdd(&cnt[v>>20], 1);
        csr[seg0 + p] = (int)(v & 0xFFFFFu);
    }
    __syncthreads();
    int sg0 = scan[(size_t)(B+b)*C] - E;
    int sg1 = ((b+1<B) ? scan[(size_t)(B+b+1)*C] : 2*E) - E;
    for (int i=t;i<range;i+=256) cnt[i]=0;
    __syncthreads();
    for (int i=sg0+t; i<sg1; i+=256)
        atomicAdd(&cnt[(int)tempS[i] - nb0], 1);
    __syncthreads();
    for (int i=t;i<range;i+=256){
        int node = nb0+i;
        if (node < N) deg_out[node] = cnt[i];
    }
}

// ============ GEMM (swapped-operand MFMA) -> fp8 output ============
__global__ __launch_bounds__(256) void k_gemm(const void* __restrict__ A,
        const uint16_t* __restrict__ Wf, const int* __restrict__ deg_out,
        uint8_t* __restrict__ out8, int nrows, int amode){
    int t = threadIdx.x;
    int wave = t>>6, lane = t&63, quad = lane>>4, low = lane&15;

    int rowA  = blockIdx.x*64 + wave*16 + low;
    int rowAc = min(rowA, nrows-1);

    bf16x8 ah[4];
    if (amode){
        const uint16_t* arow = (const uint16_t*)A + (size_t)rowAc*FD;
        #pragma unroll
        for (int kk=0;kk<4;kk++)
            ah[kk] = *(const bf16x8*)(arow + kk*32 + quad*8);
    } else {
        const float* arow = (const float*)A + (size_t)rowAc*FD;
        #pragma unroll
        for (int kk=0;kk<4;kk++){
            f32x4 f0 = *(const f32x4*)(arow + kk*32 + quad*8);
            f32x4 f1 = *(const f32x4*)(arow + kk*32 + quad*8 + 4);
            #pragma unroll
            for (int j=0;j<4;j++) ah[kk][j]   = (short)f2bf(f0[j]);
            #pragma unroll
            for (int j=0;j<4;j++) ah[kk][j+4] = (short)f2bf(f1[j]);
        }
    }

    f32x4 acc[8];
    #pragma unroll
    for (int n=0;n<8;n++) acc[n] = (f32x4){0.f,0.f,0.f,0.f};

    #pragma unroll
    for (int kk=0;kk<4;kk++){
        #pragma unroll
        for (int n=0;n<8;n++){
            bf16x8 bh = *(const bf16x8*)(Wf + ((size_t)((kk*8+n)*64 + lane))*8);
            acc[n] = __builtin_amdgcn_mfma_f32_16x16x32_bf16(bh, ah[kk], acc[n], 0, 0, 0);
        }
    }

    if (rowA < nrows){
        float sc = rsqrtf((float)max(deg_out[rowA], 1));
        uint8_t* orow = out8 + (size_t)rowA*FD;
        #pragma unroll
        for (int n=0;n<8;n++){
            uint32_t pk = pk4fp8(acc[n][0]*sc, acc[n][1]*sc, acc[n][2]*sc, acc[n][3]*sc);
            *(uint32_t*)(orow + n*16 + quad*4) = pk;
        }
    }
}

// ============ SpMM row-gather core: quarter-wave, 8B/lane, depth-8 ============
__device__ __forceinline__ void spmm_row(const uint2* __restrict__ tp,
        const int* __restrict__ csr_src, int e0, int e1, int l, int qb,
        f32x2& a01, f32x2& a23, f32x2& a45, f32x2& a67){
    for (int base = e0; base < e1; base += 16){
        int my = 0;
        if (base + l < e1) my = csr_src[base + l];
        int cnt = min(16, e1 - base);
        for (int j0 = 0; j0 < cnt; j0 += 8){
            int ss[8];
            #pragma unroll
            for (int k=0;k<8;k++)
                ss[k] = __shfl(my, qb + min(j0 + k, cnt-1));
            uint2 p[8];
            #pragma unroll
            for (int k=0;k<8;k++)
                p[k] = tp[(size_t)ss[k]*16 + l];
            #pragma unroll
            for (int k=0;k<8;k++){
                if (j0 + k < cnt){
                    a01 += fp8lo2f(p[k].x); a23 += fp8hi2f(p[k].x);
                    a45 += fp8lo2f(p[k].y); a67 += fp8hi2f(p[k].y);
                }
            }
        }
    }
}

// ============ Fused: SpMM layer-1 -> LDS h-rows -> GEMM W2 -> fp8 ============
// Block = 64 nodes. 16 quarter-waves gather 4 nodes each, write relu(h) rows
// (bf16) into LDS; after one barrier the same block runs the 64-row MFMA tile
// against Wf2 and emits the layer-2 fp8 pre-agg rows. hb is never materialized.
__global__ __launch_bounds__(256) void k_spmm_gemm(const uint8_t* __restrict__ tmp8,
        const int* __restrict__ row_off, const int* __restrict__ csr_src,
        const float* __restrict__ bias, const uint16_t* __restrict__ Wf,
        const int* __restrict__ deg_out, uint8_t* __restrict__ out8, int N){
    __shared__ __align__(16) uint16_t hsrow[64][136];   // +8 shorts pad: 2-way max on ds_read_b128
    int tid = threadIdx.x;
    int l = tid & 15, qid = tid >> 4, qb = (tid & 63) & 48;
    const uint2* tp = (const uint2*)tmp8;
    f32x4 bv0 = *(const f32x4*)(bias + l*8);
    f32x4 bv1 = *(const f32x4*)(bias + l*8 + 4);
    #pragma unroll
    for (int i = 0; i < 4; i++){
        int rowL = qid*4 + i;
        int node = blockIdx.x*64 + rowL;
        int e0 = 0, e1 = 0;
        if (node < N){ e0 = row_off[node]; e1 = row_off[node+1]; }
        f32x2 a01={0.f,0.f}, a23={0.f,0.f}, a45={0.f,0.f}, a67={0.f,0.f};
        spmm_row(tp, csr_src, e0, e1, l, qb, a01, a23, a45, a67);
        float isq = rsqrtf((float)max(e1 - e0, 1));
        float r0 = fmaxf(a01.x*isq + bv0[0], 0.f);
        float r1 = fmaxf(a01.y*isq + bv0[1], 0.f);
        float r2 = fmaxf(a23.x*isq + bv0[2], 0.f);
        float r3 = fmaxf(a23.y*isq + bv0[3], 0.f);
        float r4 = fmaxf(a45.x*isq + bv1[0], 0.f);
        float r5 = fmaxf(a45.y*isq + bv1[1], 0.f);
        float r6 = fmaxf(a67.x*isq + bv1[2], 0.f);
        float r7 = fmaxf(a67.y*isq + bv1[3], 0.f);
        uint4 o;
        o.x = (uint32_t)f2bf(r0) | ((uint32_t)f2bf(r1) << 16);
        o.y = (uint32_t)f2bf(r2) | ((uint32_t)f2bf(r3) << 16);
        o.z = (uint32_t)f2bf(r4) | ((uint32_t)f2bf(r5) << 16);
        o.w = (uint32_t)f2bf(r6) | ((uint32_t)f2bf(r7) << 16);
        if (node >= N) o = (uint4){0u,0u,0u,0u};
        *(uint4*)(&hsrow[rowL][l*8]) = o;
    }
    __syncthreads();
    // ---- GEMM phase: wave w owns rows w*16..w*16+15 of the LDS tile ----
    int wave = tid>>6, lane = tid&63, quad = lane>>4, low = lane&15;
    int rowL = wave*16 + low;
    int rowA = blockIdx.x*64 + rowL;
    bf16x8 ah[4];
    #pragma unroll
    for (int kk=0;kk<4;kk++)
        ah[kk] = *(const bf16x8*)(&hsrow[rowL][kk*32 + quad*8]);
    f32x4 acc[8];
    #pragma unroll
    for (int n=0;n<8;n++) acc[n] = (f32x4){0.f,0.f,0.f,0.f};
    #pragma unroll
    for (int kk=0;kk<4;kk++){
        #pragma unroll
        for (int n=0;n<8;n++){
            bf16x8 bh = *(const bf16x8*)(Wf + ((size_t)((kk*8+n)*64 + lane))*8);
            acc[n] = __builtin_amdgcn_mfma_f32_16x16x32_bf16(bh, ah[kk], acc[n], 0, 0, 0);
        }
    }
    if (rowA < N){
        float sc = rsqrtf((float)max(deg_out[rowA], 1));
        uint8_t* orow = out8 + (size_t)rowA*FD;
        #pragma unroll
        for (int n=0;n<8;n++){
            uint32_t pk = pk4fp8(acc[n][0]*sc, acc[n][1]*sc, acc[n][2]*sc, acc[n][3]*sc);
            *(uint32_t*)(orow + n*16 + quad*4) = pk;
        }
    }
}

// ============ Fused: SpMM layer-2 -> per-graph pool (h2 never stored) ============
__global__ __launch_bounds__(256) void k_spmm_pool(const uint8_t* __restrict__ tmp8,
        const int* __restrict__ row_off, const int* __restrict__ csr_src,
        const float* __restrict__ bias, const int* __restrict__ n2g,
        float* __restrict__ pool, int N){
    __shared__ float sacc[NG*FD];
    int tid = threadIdx.x;
    for (int i = tid; i < NG*FD; i += 256) sacc[i] = 0.f;
    __syncthreads();
    int l = tid & 15, qid = tid >> 4, qb = (tid & 63) & 48;
    const uint2* tp = (const uint2*)tmp8;
    f32x4 bv0 = *(const f32x4*)(bias + l*8);
    f32x4 bv1 = *(const f32x4*)(bias + l*8 + 4);
    int rg = -1;
    float racc[8];
    #pragma unroll
    for (int j=0;j<8;j++) racc[j] = 0.f;
    #pragma unroll
    for (int i = 0; i < 4; i++){
        int node = blockIdx.x*64 + qid*4 + i;
        if (node < N){
            int e0 = row_off[node], e1 = row_off[node+1];
            f32x2 a01={0.f,0.f}, a23={0.f,0.f}, a45={0.f,0.f}, a67={0.f,0.f};
            spmm_row(tp, csr_src, e0, e1, l, qb, a01, a23, a45, a67);
            float isq = rsqrtf((float)max(e1 - e0, 1));
            float r[8];
            r[0] = fmaxf(a01.x*isq + bv0[0], 0.f);
            r[1] = fmaxf(a01.y*isq + bv0[1], 0.f);
            r[2] = fmaxf(a23.x*isq + bv0[2], 0.f);
            r[3] = fmaxf(a23.y*isq + bv0[3], 0.f);
            r[4] = fmaxf(a45.x*isq + bv1[0], 0.f);
            r[5] = fmaxf(a45.y*isq + bv1[1], 0.f);
            r[6] = fmaxf(a67.x*isq + bv1[2], 0.f);
            r[7] = fmaxf(a67.y*isq + bv1[3], 0.f);
            int g = n2g[node];
            if (g != rg){
                if (rg >= 0){
                    #pragma unroll
                    for (int j=0;j<8;j++) atomicAdd(&sacc[rg*FD + l*8 + j], racc[j]);
                }
                rg = g;
                #pragma unroll
                for (int j=0;j<8;j++) racc[j] = 0.f;
            }
            #pragma unroll
            for (int j=0;j<8;j++) racc[j] += r[j];
        }
    }
    if (rg >= 0){
        #pragma unroll
        for (int j=0;j<8;j++) atomicAdd(&sacc[rg*FD + l*8 + j], racc[j]);
    }
    __syncthreads();
    for (int i = tid; i < NG*FD; i += 256){
        float v = sacc[i];
        if (v != 0.f) atomicAdd(&pool[i], v);
    }
}

// ============ mean, linear, softmax -> 80 f32 ============
__global__ __launch_bounds__(128) void k_final(const float* __restrict__ pool,
        const int* __restrict__ n2g, int N, const float* __restrict__ Wl,
        const float* __restrict__ bl, float* __restrict__ out){
    __shared__ int ub[NG+1];
    __shared__ float logits[NG][NC];
    int t = threadIdx.x;
    if (t <= NG){
        int lo = 0, hi = N;
        while (lo < hi){ int mid = (lo+hi)>>1; if (n2g[mid] < t) lo = mid+1; else hi = mid; }
        ub[t] = lo;
    }
    __syncthreads();
    if (t < NG*NC){
        int g = t/NC, c = t%NC;
        float cnt = (float)max(ub[g+1]-ub[g], 1);
        float inv = 1.f/cnt;
        float acc = bl[c];
        for (int d=0; d<FD; d++)
            acc += pool[g*FD+d]*inv * Wl[d*NC+c];
        logits[g][c] = acc;
    }
    __syncthreads();
    if (t < NG*NC){
        int g = t/NC, c = t%NC;
        float m = -1e30f;
        for (int i=0;i<NC;i++) m = fmaxf(m, logits[g][i]);
        float ssum = 0.f;
        for (int i=0;i<NC;i++) ssum += expf(logits[g][i]-m);
        out[t] = expf(logits[g][c]-m)/ssum;
    }
}

extern "C" void kernel_launch(void* const* d_in, const int* in_sizes, int n_in,
                              void* d_out, int out_size, void* d_ws, size_t ws_size,
                              hipStream_t stream) {
    const float* x   = (const float*)d_in[0];
    const int*   ei  = (const int*)d_in[1];
    const int*   n2g = (const int*)d_in[2];
    const float* W1  = (const float*)d_in[3];
    const float* b1  = (const float*)d_in[4];
    const float* W2  = (const float*)d_in[5];
    const float* b2  = (const float*)d_in[6];
    const float* Wl  = (const float*)d_in[7];
    const float* bl  = (const float*)d_in[8];
    float* outp = (float*)d_out;

    int N = in_sizes[2];
    int E = in_sizes[1] / 2;

    int shift = 6;
    while ((((N + (1<<shift) - 1) >> shift) > MAXB) && shift < 10) shift++;
    int B = (N + (1<<shift) - 1) >> shift;
    int C = (E + CHUNK - 1) / CHUNK;
    int M = 2*B*C;
    int nscan = (M + STILE - 1) / STILE;   // <= 1024 (state array)

    char* w = (char*)d_ws;
    size_t off = 0;
    auto alloc = [&](size_t bytes)->char*{ char* p = w + off; off += (bytes + 255) & ~(size_t)255; return p; };
    float*    pool    = (float*)alloc((size_t)NG*FD*4);
    unsigned long long* state = (unsigned long long*)alloc(1024*8);
    int*      counters= (int*)alloc(8*4);       // [0]=scan ticket
    int*      deg_out = (int*)alloc((size_t)N*4);
    int*      row_off = (int*)alloc((size_t)(N+1)*4);
    int*      csr     = (int*)alloc((size_t)E*4);
    uint16_t* Wf1     = (uint16_t*)alloc(16384*2);
    uint16_t* Wf2     = (uint16_t*)alloc(16384*2);
    uint8_t*  tmp8    = (uint8_t*)alloc((size_t)N*FD);   // layer-1 fp8 pre-agg rows
    uint8_t*  tmp8b   = (uint8_t*)alloc((size_t)N*FD);   // layer-2 fp8 pre-agg rows
    int*      cnt     = (int*)alloc((size_t)M*4);
    (void)ws_size;
    // aliases (live only during CSR build, before tmp8 is written)
    uint32_t* tempD = (uint32_t*)tmp8;                      // E*4 <= N*FD
    uint16_t* tempS = (uint16_t*)(tmp8 + (size_t)E*4);      // +E*2

    k_prep   <<<128 + C, 256, 0, stream>>>(W1, W2, Wf1, Wf2, ei, E, B, C, shift,
                                           cnt, pool, state, counters);
    k_scan   <<<nscan, 256, 0, stream>>>(cnt, M, state, &counters[0]);
    k_scatter<<<C, 256, 0, stream>>>(ei, E, B, C, shift, cnt, tempD, tempS);
    k_build2 <<<B, 256, 0, stream>>>(tempD, tempS, cnt, B, C, shift, E, N, row_off, csr, deg_out);

    int gb = (N + 63)/64;
    k_gemm      <<<gb, 256, 0, stream>>>(x, Wf1, deg_out, tmp8, N, 0);
    k_spmm_gemm <<<gb, 256, 0, stream>>>(tmp8,  row_off, csr, b1, Wf2, deg_out, tmp8b, N);
    k_spmm_pool <<<gb, 256, 0, stream>>>(tmp8b, row_off, csr, b2, n2g, pool, N);
    k_final     <<<1,  128, 0, stream>>>(pool, n2g, N, Wl, bl, outp);
}

// Round 2
// 218.621 us; speedup vs baseline: 1.0214x; 1.0214x over previous
//
#include <hip/hip_runtime.h>
#include <stdint.h>

#define FD 128   // feature dim
#define NG 8     // graphs
#define NC 10    // classes
#define MAXB 1024           // max buckets
#define CHUNK 4096          // edges per scatter chunk (16/thread)

typedef __attribute__((ext_vector_type(8))) short bf16x8;
typedef __attribute__((ext_vector_type(4))) float f32x4;
typedef __attribute__((ext_vector_type(2))) float f32x2;

__device__ __forceinline__ float bf2f(uint16_t u){
    union { uint32_t i; float f; } v; v.i = ((uint32_t)u) << 16; return v.f;
}
__device__ __forceinline__ uint16_t f2bf(float f){
    union { float f; uint32_t i; } v; v.f = f;
    uint32_t r = v.i + 0x7fff + ((v.i >> 16) & 1);
    return (uint16_t)(r >> 16);
}

// ---- fp8 e4m3 conversions (HW path with manual fallback) ----
#if __has_builtin(__builtin_amdgcn_cvt_pk_f32_fp8) && __has_builtin(__builtin_amdgcn_cvt_pk_fp8_f32)
__device__ __forceinline__ f32x2 fp8lo2f(uint32_t p){
    return __builtin_amdgcn_cvt_pk_f32_fp8((int)p, false);
}
__device__ __forceinline__ f32x2 fp8hi2f(uint32_t p){
    return __builtin_amdgcn_cvt_pk_f32_fp8((int)p, true);
}
__device__ __forceinline__ uint32_t pk4fp8(float a, float b, float c, float d){
    int u = 0;
    u = __builtin_amdgcn_cvt_pk_fp8_f32(a, b, u, false);
    u = __builtin_amdgcn_cvt_pk_fp8_f32(c, d, u, true);
    return (uint32_t)u;
}
#else
__device__ __forceinline__ float fp8tof(uint32_t b){
    union { uint32_t i; float f; } v;
    v.i = ((b & 0x7f) << 20) | ((b & 0x80) << 24);
    return v.f * 0x1p120f;
}
__device__ __forceinline__ f32x2 fp8lo2f(uint32_t p){
    return (f32x2){fp8tof(p & 0xff), fp8tof((p >> 8) & 0xff)};
}
__device__ __forceinline__ f32x2 fp8hi2f(uint32_t p){
    return (f32x2){fp8tof((p >> 16) & 0xff), fp8tof((p >> 24) & 0xff)};
}
__device__ __forceinline__ uint32_t f2fp8(float f){
    union { float f; uint32_t i; } v; v.f = f;
    uint32_t s = (v.i >> 24) & 0x80;
    float a = fabsf(f);
    if (a < 0x1p-10f) return s;
    if (a > 448.f) return s | 0x7e;
    v.f = a;
    uint32_t r = v.i + 0x7ffff + ((v.i >> 20) & 1);
    int e = (int)(r >> 23) - 127 + 7;
    uint32_t m = (r >> 20) & 7;
    if (e <= 0){
        uint32_t q = (uint32_t)(a * 512.f + 0.5f);
        return s | (q > 7 ? 8 : q);
    }
    if (e > 15) return s | 0x7e;
    return s | ((uint32_t)e << 3) | m;
}
__device__ __forceinline__ uint32_t pk4fp8(float a, float b, float c, float d){
    return (uint32_t)f2fp8(a) | ((uint32_t)f2fp8(b)<<8) |
           ((uint32_t)f2fp8(c)<<16) | ((uint32_t)f2fp8(d)<<24);
}
#endif

// ============ prep: weight conversion + zero-init (no edge work) ============
__global__ __launch_bounds__(256) void k_prep(const float* __restrict__ W1,
        const float* __restrict__ W2, uint16_t* Wf1, uint16_t* Wf2,
        int N, int B, int* __restrict__ deg_out, int* __restrict__ bucket_fill,
        float* __restrict__ pool){
    int t = threadIdx.x;
    int id = blockIdx.x*256 + t;           // grid = 128 blocks -> 32768 threads
    {   // weight fragment conversion (exactly 2*16384 entries)
        int w = id >> 14;
        int r = id & 16383;
        int j = r & 7, frag = r >> 3;
        int lane = frag & 63, t2 = frag >> 6;
        int n = t2 & 7, kk = t2 >> 3;
        int k = kk*32 + (lane>>4)*8 + j;
        int col = n*16 + (lane&15);
        float v = (w ? W2 : W1)[k*128 + col];
        (w ? Wf2 : Wf1)[r] = f2bf(v);
    }
    for (int i = id; i < N; i += 32768) deg_out[i] = 0;
    for (int i = id; i < B; i += 32768) bucket_fill[i] = 0;
    if (id < NG*FD) pool[id] = 0.f;
}

// ============ single-pass hist + reserve + scatter (fixed-cap buckets) ============
// No global scan: bucket b owns slots [b*CAP, b*CAP+CAP). Blocks reserve
// ranges with one atomicAdd per touched bucket; edge order within a bucket
// is arbitrary (k_build re-sorts per node; sum order is numerically moot).
__global__ __launch_bounds__(256) void k_scatter(const int* __restrict__ ei,
        int E, int B, int shift, int CAP,
        int* __restrict__ bucket_fill, int* __restrict__ deg_out,
        uint32_t* __restrict__ tempD){
    __shared__ int hc[MAXB];    // chunk counts, then per-bucket cursors
    __shared__ int hb_[MAXB];   // reserved base for this block
    int t = threadIdx.x, c = blockIdx.x;
    for (int i=t;i<B;i+=256) hc[i]=0;
    __syncthreads();
    int e0 = c*CHUNK, e1 = min(E, e0+CHUNK);
    int ss[16], dd[16];
    #pragma unroll
    for (int k=0;k<16;k++){
        int e = e0 + t + k*256;
        bool ok = e < e1;
        int s = ok ? ei[e]   : 0;
        int d = ok ? ei[E+e] : 0;
        ss[k] = s; dd[k] = ok ? d : -1;
        if (ok){
            atomicAdd(&hc[d>>shift], 1);
            atomicAdd(&deg_out[s], 1);
        }
    }
    __syncthreads();
    for (int i=t;i<B;i+=256){
        int cn = hc[i];
        hb_[i] = cn ? atomicAdd(&bucket_fill[i], cn) : 0;
    }
    __syncthreads();
    for (int i=t;i<B;i+=256) hc[i]=0;
    __syncthreads();
    int lmask = (1<<shift) - 1;
    #pragma unroll
    for (int k=0;k<16;k++){
        int d = dd[k];
        if (d >= 0){
            int b = d >> shift;
            int p = hb_[b] + atomicAdd(&hc[b], 1);
            if (p < CAP)
                tempD[(size_t)b*CAP + p] = ((uint32_t)(d & lmask) << 20) | (uint32_t)ss[k];
        }
    }
}

// ============ per-bucket: row_off + deg_in + node-sorted csr (strided) ============
__global__ __launch_bounds__(256) void k_build(const uint32_t* __restrict__ tempD,
        const int* __restrict__ bucket_fill, int B, int shift, int N, int CAP,
        int* __restrict__ row_off, int* __restrict__ deg_in, int* __restrict__ csr){
    __shared__ int cnt_[MAXB];
    __shared__ int off_[MAXB];
    int b = blockIdx.x, t = threadIdx.x;
    int range = 1<<shift, nb0 = b<<shift;
    int fill = min(bucket_fill[b], CAP);
    const uint32_t* seg = tempD + (size_t)b*CAP;
    for (int i=t;i<range;i+=256) cnt_[i]=0;
    __syncthreads();
    for (int i=t;i<fill;i+=256)
        atomicAdd(&cnt_[seg[i]>>20], 1);
    __syncthreads();
    if (range == 64){
        if (t < 64){
            int v = cnt_[t];
            int inc = v;
            #pragma unroll
            for (int o=1;o<64;o<<=1){
                int u = __shfl_up(inc, o);
                if (t >= o) inc += u;
            }
            off_[t] = inc - v;
        }
    } else if (t == 0){
        int run = 0;
        for (int i=0;i<range;i++){ off_[i]=run; run+=cnt_[i]; }
    }
    __syncthreads();
    int base = b*CAP;
    for (int i=t;i<range;i+=256){
        int node = nb0 + i;
        if (node < N){
            row_off[node] = base + off_[i];
            deg_in[node]  = cnt_[i];
        }
    }
    __syncthreads();
    int* csrb = csr + (size_t)base;
    for (int i=t;i<fill;i+=256){
        uint32_t v = seg[i];
        int p = atomicAdd(&off_[v>>20], 1);
        csrb[p] = (int)(v & 0xFFFFFu);
    }
}

// ============ GEMM (swapped-operand MFMA) -> fp8 output ============
__global__ __launch_bounds__(256) void k_gemm(const void* __restrict__ A,
        const uint16_t* __restrict__ Wf, const int* __restrict__ deg_out,
        uint8_t* __restrict__ out8, int nrows, int amode){
    int t = threadIdx.x;
    int wave = t>>6, lane = t&63, quad = lane>>4, low = lane&15;

    int rowA  = blockIdx.x*64 + wave*16 + low;
    int rowAc = min(rowA, nrows-1);

    bf16x8 ah[4];
    if (amode){
        const uint16_t* arow = (const uint16_t*)A + (size_t)rowAc*FD;
        #pragma unroll
        for (int kk=0;kk<4;kk++)
            ah[kk] = *(const bf16x8*)(arow + kk*32 + quad*8);
    } else {
        const float* arow = (const float*)A + (size_t)rowAc*FD;
        #pragma unroll
        for (int kk=0;kk<4;kk++){
            f32x4 f0 = *(const f32x4*)(arow + kk*32 + quad*8);
            f32x4 f1 = *(const f32x4*)(arow + kk*32 + quad*8 + 4);
            #pragma unroll
            for (int j=0;j<4;j++) ah[kk][j]   = (short)f2bf(f0[j]);
            #pragma unroll
            for (int j=0;j<4;j++) ah[kk][j+4] = (short)f2bf(f1[j]);
        }
    }

    f32x4 acc[8];
    #pragma unroll
    for (int n=0;n<8;n++) acc[n] = (f32x4){0.f,0.f,0.f,0.f};

    #pragma unroll
    for (int kk=0;kk<4;kk++){
        #pragma unroll
        for (int n=0;n<8;n++){
            bf16x8 bh = *(const bf16x8*)(Wf + ((size_t)((kk*8+n)*64 + lane))*8);
            acc[n] = __builtin_amdgcn_mfma_f32_16x16x32_bf16(bh, ah[kk], acc[n], 0, 0, 0);
        }
    }

    if (rowA < nrows){
        float sc = rsqrtf((float)max(deg_out[rowA], 1));
        uint8_t* orow = out8 + (size_t)rowA*FD;
        #pragma unroll
        for (int n=0;n<8;n++){
            uint32_t pk = pk4fp8(acc[n][0]*sc, acc[n][1]*sc, acc[n][2]*sc, acc[n][3]*sc);
            *(uint32_t*)(orow + n*16 + quad*4) = pk;
        }
    }
}

// ============ SpMM row-gather core: quarter-wave, 8B/lane, depth-8 ============
__device__ __forceinline__ void spmm_row(const uint2* __restrict__ tp,
        const int* __restrict__ csr_src, int e0, int e1, int l, int qb,
        f32x2& a01, f32x2& a23, f32x2& a45, f32x2& a67){
    for (int base = e0; base < e1; base += 16){
        int my = 0;
        if (base + l < e1) my = csr_src[base + l];
        int cnt = min(16, e1 - base);
        for (int j0 = 0; j0 < cnt; j0 += 8){
            int ss[8];
            #pragma unroll
            for (int k=0;k<8;k++)
                ss[k] = __shfl(my, qb + min(j0 + k, cnt-1));
            uint2 p[8];
            #pragma unroll
            for (int k=0;k<8;k++)
                p[k] = tp[(size_t)ss[k]*16 + l];
            #pragma unroll
            for (int k=0;k<8;k++){
                if (j0 + k < cnt){
                    a01 += fp8lo2f(p[k].x); a23 += fp8hi2f(p[k].x);
                    a45 += fp8lo2f(p[k].y); a67 += fp8hi2f(p[k].y);
                }
            }
        }
    }
}

// ============ Fused: SpMM layer-1 -> LDS h-rows -> GEMM W2 -> fp8 ============
__global__ __launch_bounds__(256) void k_spmm_gemm(const uint8_t* __restrict__ tmp8,
        const int* __restrict__ row_off, const int* __restrict__ deg_in,
        const int* __restrict__ csr_src,
        const float* __restrict__ bias, const uint16_t* __restrict__ Wf,
        const int* __restrict__ deg_out, uint8_t* __restrict__ out8, int N){
    __shared__ __align__(16) uint16_t hsrow[64][136];   // +8 shorts pad
    int tid = threadIdx.x;
    int l = tid & 15, qid = tid >> 4, qb = (tid & 63) & 48;
    const uint2* tp = (const uint2*)tmp8;
    f32x4 bv0 = *(const f32x4*)(bias + l*8);
    f32x4 bv1 = *(const f32x4*)(bias + l*8 + 4);
    #pragma unroll
    for (int i = 0; i < 4; i++){
        int rowL = qid*4 + i;
        int node = blockIdx.x*64 + rowL;
        int e0 = 0, e1 = 0;
        if (node < N){ e0 = row_off[node]; e1 = e0 + deg_in[node]; }
        f32x2 a01={0.f,0.f}, a23={0.f,0.f}, a45={0.f,0.f}, a67={0.f,0.f};
        spmm_row(tp, csr_src, e0, e1, l, qb, a01, a23, a45, a67);
        float isq = rsqrtf((float)max(e1 - e0, 1));
        float r0 = fmaxf(a01.x*isq + bv0[0], 0.f);
        float r1 = fmaxf(a01.y*isq + bv0[1], 0.f);
        float r2 = fmaxf(a23.x*isq + bv0[2], 0.f);
        float r3 = fmaxf(a23.y*isq + bv0[3], 0.f);
        float r4 = fmaxf(a45.x*isq + bv1[0], 0.f);
        float r5 = fmaxf(a45.y*isq + bv1[1], 0.f);
        float r6 = fmaxf(a67.x*isq + bv1[2], 0.f);
        float r7 = fmaxf(a67.y*isq + bv1[3], 0.f);
        uint4 o;
        o.x = (uint32_t)f2bf(r0) | ((uint32_t)f2bf(r1) << 16);
        o.y = (uint32_t)f2bf(r2) | ((uint32_t)f2bf(r3) << 16);
        o.z = (uint32_t)f2bf(r4) | ((uint32_t)f2bf(r5) << 16);
        o.w = (uint32_t)f2bf(r6) | ((uint32_t)f2bf(r7) << 16);
        if (node >= N) o = (uint4){0u,0u,0u,0u};
        *(uint4*)(&hsrow[rowL][l*8]) = o;
    }
    __syncthreads();
    // ---- GEMM phase: wave w owns rows w*16..w*16+15 of the LDS tile ----
    int wave = tid>>6, lane = tid&63, quad = lane>>4, low = lane&15;
    int rowL = wave*16 + low;
    int rowA = blockIdx.x*64 + rowL;
    bf16x8 ah[4];
    #pragma unroll
    for (int kk=0;kk<4;kk++)
        ah[kk] = *(const bf16x8*)(&hsrow[rowL][kk*32 + quad*8]);
    f32x4 acc[8];
    #pragma unroll
    for (int n=0;n<8;n++) acc[n] = (f32x4){0.f,0.f,0.f,0.f};
    #pragma unroll
    for (int kk=0;kk<4;kk++){
        #pragma unroll
        for (int n=0;n<8;n++){
            bf16x8 bh = *(const bf16x8*)(Wf + ((size_t)((kk*8+n)*64 + lane))*8);
            acc[n] = __builtin_amdgcn_mfma_f32_16x16x32_bf16(bh, ah[kk], acc[n], 0, 0, 0);
        }
    }
    if (rowA < N){
        float sc = rsqrtf((float)max(deg_out[rowA], 1));
        uint8_t* orow = out8 + (size_t)rowA*FD;
        #pragma unroll
        for (int n=0;n<8;n++){
            uint32_t pk = pk4fp8(acc[n][0]*sc, acc[n][1]*sc, acc[n][2]*sc, acc[n][3]*sc);
            *(uint32_t*)(orow + n*16 + quad*4) = pk;
        }
    }
}

// ============ Fused: SpMM layer-2 -> per-graph pool (h2 never stored) ============
__global__ __launch_bounds__(256) void k_spmm_pool(const uint8_t* __restrict__ tmp8,
        const int* __restrict__ row_off, const int* __restrict__ deg_in,
        const int* __restrict__ csr_src,
        const float* __restrict__ bias, const int* __restrict__ n2g,
        float* __restrict__ pool, int N){
    __shared__ float sacc[NG*FD];
    int tid = threadIdx.x;
    for (int i = tid; i < NG*FD; i += 256) sacc[i] = 0.f;
    __syncthreads();
    int l = tid & 15, qid = tid >> 4, qb = (tid & 63) & 48;
    const uint2* tp = (const uint2*)tmp8;
    f32x4 bv0 = *(const f32x4*)(bias + l*8);
    f32x4 bv1 = *(const f32x4*)(bias + l*8 + 4);
    int rg = -1;
    float racc[8];
    #pragma unroll
    for (int j=0;j<8;j++) racc[j] = 0.f;
    #pragma unroll
    for (int i = 0; i < 4; i++){
        int node = blockIdx.x*64 + qid*4 + i;
        if (node < N){
            int e0 = row_off[node], e1 = e0 + deg_in[node];
            f32x2 a01={0.f,0.f}, a23={0.f,0.f}, a45={0.f,0.f}, a67={0.f,0.f};
            spmm_row(tp, csr_src, e0, e1, l, qb, a01, a23, a45, a67);
            float isq = rsqrtf((float)max(e1 - e0, 1));
            float r[8];
            r[0] = fmaxf(a01.x*isq + bv0[0], 0.f);
            r[1] = fmaxf(a01.y*isq + bv0[1], 0.f);
            r[2] = fmaxf(a23.x*isq + bv0[2], 0.f);
            r[3] = fmaxf(a23.y*isq + bv0[3], 0.f);
            r[4] = fmaxf(a45.x*isq + bv1[0], 0.f);
            r[5] = fmaxf(a45.y*isq + bv1[1], 0.f);
            r[6] = fmaxf(a67.x*isq + bv1[2], 0.f);
            r[7] = fmaxf(a67.y*isq + bv1[3], 0.f);
            int g = n2g[node];
            if (g != rg){
                if (rg >= 0){
                    #pragma unroll
                    for (int j=0;j<8;j++) atomicAdd(&sacc[rg*FD + l*8 + j], racc[j]);
                }
                rg = g;
                #pragma unroll
                for (int j=0;j<8;j++) racc[j] = 0.f;
            }
            #pragma unroll
            for (int j=0;j<8;j++) racc[j] += r[j];
        }
    }
    if (rg >= 0){
        #pragma unroll
        for (int j=0;j<8;j++) atomicAdd(&sacc[rg*FD + l*8 + j], racc[j]);
    }
    __syncthreads();
    for (int i = tid; i < NG*FD; i += 256){
        float v = sacc[i];
        if (v != 0.f) atomicAdd(&pool[i], v);
    }
}

// ============ mean, linear, softmax -> 80 f32 ============
__global__ __launch_bounds__(128) void k_final(const float* __restrict__ pool,
        const int* __restrict__ n2g, int N, const float* __restrict__ Wl,
        const float* __restrict__ bl, float* __restrict__ out){
    __shared__ int ub[NG+1];
    __shared__ float logits[NG][NC];
    int t = threadIdx.x;
    if (t <= NG){
        int lo = 0, hi = N;
        while (lo < hi){ int mid = (lo+hi)>>1; if (n2g[mid] < t) lo = mid+1; else hi = mid; }
        ub[t] = lo;
    }
    __syncthreads();
    if (t < NG*NC){
        int g = t/NC, c = t%NC;
        float cnt = (float)max(ub[g+1]-ub[g], 1);
        float inv = 1.f/cnt;
        float acc = bl[c];
        for (int d=0; d<FD; d++)
            acc += pool[g*FD+d]*inv * Wl[d*NC+c];
        logits[g][c] = acc;
    }
    __syncthreads();
    if (t < NG*NC){
        int g = t/NC, c = t%NC;
        float m = -1e30f;
        for (int i=0;i<NC;i++) m = fmaxf(m, logits[g][i]);
        float ssum = 0.f;
        for (int i=0;i<NC;i++) ssum += expf(logits[g][i]-m);
        out[t] = expf(logits[g][c]-m)/ssum;
    }
}

extern "C" void kernel_launch(void* const* d_in, const int* in_sizes, int n_in,
                              void* d_out, int out_size, void* d_ws, size_t ws_size,
                              hipStream_t stream) {
    const float* x   = (const float*)d_in[0];
    const int*   ei  = (const int*)d_in[1];
    const int*   n2g = (const int*)d_in[2];
    const float* W1  = (const float*)d_in[3];
    const float* b1  = (const float*)d_in[4];
    const float* W2  = (const float*)d_in[5];
    const float* b2  = (const float*)d_in[6];
    const float* Wl  = (const float*)d_in[7];
    const float* bl  = (const float*)d_in[8];
    float* outp = (float*)d_out;

    int N = in_sizes[2];
    int E = in_sizes[1] / 2;

    int shift = 6;
    while ((((N + (1<<shift) - 1) >> shift) > MAXB) && shift < 10) shift++;
    int B = (N + (1<<shift) - 1) >> shift;
    int C = (E + CHUNK - 1) / CHUNK;
    // fixed bucket capacity: mean fill = E*2^shift/N (~1024 here); 4x headroom
    int meanFill = (int)(((long long)E << shift) / (N > 0 ? N : 1)) + 1;
    int CAP = 4096;
    while (CAP < 4*meanFill) CAP <<= 1;

    char* w = (char*)d_ws;
    size_t off = 0;
    auto alloc = [&](size_t bytes)->char*{ char* p = w + off; off += (bytes + 255) & ~(size_t)255; return p; };
    float*    pool        = (float*)alloc((size_t)NG*FD*4);
    int*      deg_out     = (int*)alloc((size_t)N*4);
    int*      deg_in      = (int*)alloc((size_t)N*4);
    int*      row_off     = (int*)alloc((size_t)N*4);
    int*      bucket_fill = (int*)alloc((size_t)MAXB*4);
    uint16_t* Wf1         = (uint16_t*)alloc(16384*2);
    uint16_t* Wf2         = (uint16_t*)alloc(16384*2);
    uint32_t* tempD       = (uint32_t*)alloc((size_t)B*CAP*4);
    int*      csr         = (int*)alloc((size_t)B*CAP*4);
    uint8_t*  tmp8        = (uint8_t*)alloc((size_t)N*FD);   // layer-1 fp8 pre-agg rows
    uint8_t*  tmp8b       = (uint8_t*)alloc((size_t)N*FD);   // layer-2 fp8 pre-agg rows
    (void)ws_size;

    k_prep   <<<128, 256, 0, stream>>>(W1, W2, Wf1, Wf2, N, B, deg_out, bucket_fill, pool);
    k_scatter<<<C,   256, 0, stream>>>(ei, E, B, shift, CAP, bucket_fill, deg_out, tempD);
    k_build  <<<B,   256, 0, stream>>>(tempD, bucket_fill, B, shift, N, CAP, row_off, deg_in, csr);

    int gb = (N + 63)/64;
    k_gemm      <<<gb, 256, 0, stream>>>(x, Wf1, deg_out, tmp8, N, 0);
    k_spmm_gemm <<<gb, 256, 0, stream>>>(tmp8,  row_off, deg_in, csr, b1, Wf2, deg_out, tmp8b, N);
    k_spmm_pool <<<gb, 256, 0, stream>>>(tmp8b, row_off, deg_in, csr, b2, n2g, pool, N);
    k_final     <<<1,  128, 0, stream>>>(pool, n2g, N, Wl, bl, outp);
}